// Round 7
// baseline (168.245 us; speedup 1.0000x reference)
//
#include <hip/hip_runtime.h>
#include <stdint.h>

#define OUT_F   4096
#define IN_F    11008
#define BATCH   64
#define NSUP    43                  // super-blocks per row
#define SB_ROW  344                 // sub-blocks per row
#define IPR     5504                // int32 elements per weight row
#define NKS     16                  // K-splits: 11 of 3 sups + 5 of 2 sups
#define NCB     32                  // col-blocks of 128
#define XP_BYTES   (344 * 256 * 16)                 // 1,409,024
#define SCMN_BYTES (NSUP * 4096 * 16)               // 2,818,048
#define DDM_BYTES  (NSUP * 4096 * 8)                // 1,409,024
#define PART_OFF   (XP_BYTES + SCMN_BYTES + DDM_BYTES)
#define PART_BYTES ((size_t)NKS * BATCH * OUT_F * 4)
#define WS_FULL    (PART_OFF + PART_BYTES)

typedef __attribute__((ext_vector_type(8))) short  short8;
typedef __attribute__((ext_vector_type(4))) float  floatx4;
typedef __attribute__((ext_vector_type(4))) int    intx4;

__device__ __forceinline__ unsigned pack_bf16(float f0, float f1) {
    return __builtin_amdgcn_perm(__float_as_uint(f1), __float_as_uint(f0), 0x07060302u);
}

// ---- pre-pack x into MFMA A-fragment order: xp[(mt*344 + ksb)*64 + l] ----
__global__ __launch_bounds__(256) void xprep_kernel(const float* __restrict__ x,
                                                    intx4* __restrict__ xp) {
    const int ksb = blockIdx.x;            // 0..343
    const int mt  = threadIdx.x >> 6;
    const int l   = threadIdx.x & 63;
    const int lo  = l & 15, hi = l >> 4;
    const float* src = x + (mt * 16 + lo) * IN_F + ksb * 32 + hi * 8;
    floatx4 a0 = *(const floatx4*)src;
    floatx4 a1 = *(const floatx4*)(src + 4);
    intx4 r;
    r.x = pack_bf16(a0.x, a0.y);
    r.y = pack_bf16(a0.z, a0.w);
    r.z = pack_bf16(a1.x, a1.y);
    r.w = pack_bf16(a1.z, a1.w);
    xp[(mt * 344 + ksb) * 64 + l] = r;
}

// ---- pack scales/mins to int8 [sup][row][16B], d/dmin to float2 [sup][row] ----
__global__ __launch_bounds__(256) void scprep_kernel(const int* __restrict__ scales,
                                                     const int* __restrict__ mins,
                                                     const float* __restrict__ dd,
                                                     const float* __restrict__ dmn,
                                                     intx4* __restrict__ scmn_p,
                                                     float2* __restrict__ ddm_p) {
    const int tg  = blockIdx.x * 256 + threadIdx.x;   // 0..176127
    const int row = tg / 43;
    const int sup = tg - row * 43;
    const intx4 s0 = *(const intx4*)(scales + row * SB_ROW + sup * 8);
    const intx4 s1 = *(const intx4*)(scales + row * SB_ROW + sup * 8 + 4);
    const intx4 m0 = *(const intx4*)(mins   + row * SB_ROW + sup * 8);
    const intx4 m1 = *(const intx4*)(mins   + row * SB_ROW + sup * 8 + 4);
    intx4 o;
    o.x = s0.x | (s0.y << 8) | (s0.z << 16) | (s0.w << 24);
    o.y = s1.x | (s1.y << 8) | (s1.z << 16) | (s1.w << 24);
    o.z = m0.x | (m0.y << 8) | (m0.z << 16) | (m0.w << 24);
    o.w = m1.x | (m1.y << 8) | (m1.z << 16) | (m1.w << 24);
    scmn_p[sup * 4096 + row] = o;
    float2 dp;
    dp.x = dd[row * NSUP + sup];
    dp.y = dmn[row * NSUP + sup];
    ddm_p[sup * 4096 + row] = dp;
}

__global__ __launch_bounds__(256) void init_out_kernel(const float* __restrict__ bias,
                                                       float* __restrict__ out) {
    int i = blockIdx.x * 256 + threadIdx.x;
    out[i] = bias[i & (OUT_F - 1)];
}

__global__ __launch_bounds__(256) void reduce_kernel(const float* __restrict__ part,
                                                     const float* __restrict__ bias,
                                                     float* __restrict__ out) {
    const int i = blockIdx.x * 256 + threadIdx.x;
    float s = bias[i & (OUT_F - 1)];
    #pragma unroll
    for (int k = 0; k < NKS; ++k) s += part[(size_t)k * (BATCH * OUT_F) + i];
    out[i] = s;
}

// block = 128 out-cols x 64 batch. LDS-dbuf, ONE barrier per super-block.
// Wave w owns n-tiles {2w, 2w+1}; acc[mt][nt] 4x2.
template<bool USE_PART>
__global__ __launch_bounds__(256, 2) void qlin_main(
    const intx4*  __restrict__ xp,
    const int*    __restrict__ packed,
    const intx4*  __restrict__ scmn_p,
    const float2* __restrict__ ddm_p,
    float*        __restrict__ part,
    float*        __restrict__ out)
{
    __shared__ intx4  xfs[2][2048];   // 64KB: x fragments, [buf][mt*512+st*64+l]
    __shared__ intx4  scs[2][128];    // 4KB : packed sc/mn bytes per row
    __shared__ float2 dds[2][128];    // 2KB : d, dmin per row

    const int ks  = blockIdx.x & 15;
    const int nb  = blockIdx.x >> 4;
    const int tid = threadIdx.x;
    const int w   = tid >> 6;
    const int l   = tid & 63;
    const int lo  = l & 15, hi = l >> 4;

    const int sup0 = ks < 11 ? 3 * ks : 33 + 2 * (ks - 11);
    const int nsup = ks < 11 ? 3 : 2;

    const int o0 = nb * 128 + (2 * w) * 16 + lo;
    const int o1 = o0 + 16;
    const int* bpA0 = packed + o0 * IPR + hi * 4;
    const int* bpA1 = packed + o1 * IPR + hi * 4;

    floatx4 acc[4][2];
    #pragma unroll
    for (int mt = 0; mt < 4; ++mt) { acc[mt][0] = (floatx4)0.0f; acc[mt][1] = (floatx4)0.0f; }

    intx4 xtmp[8]; intx4 sctv; float2 ddv;

    auto stage_issue = [&](int sup) {
        const intx4* xsrc = xp + sup * 512;
        #pragma unroll
        for (int i = 0; i < 8; ++i) {
            const int idx = i * 256 + tid;
            xtmp[i] = xsrc[(idx >> 9) * 22016 + (idx & 511)];
        }
        if (tid < 128) sctv = scmn_p[sup * 4096 + nb * 128 + tid];
        else           ddv  = ddm_p[sup * 4096 + nb * 128 + (tid - 128)];
    };
    auto stage_commit = [&](int b) {
        #pragma unroll
        for (int i = 0; i < 8; ++i) xfs[b][i * 256 + tid] = xtmp[i];
        if (tid < 128) scs[b][tid] = sctv;
        else           dds[b][tid - 128] = ddv;
    };

    struct Half { intx4 v[2][4]; };
    auto load_half = [&](int sup, int half) {
        Half r;
        #pragma unroll
        for (int st = 0; st < 4; ++st) {
            r.v[0][st] = __builtin_nontemporal_load(
                (const intx4*)(bpA0 + sup * 128 + half * 64 + st * 16));
            r.v[1][st] = __builtin_nontemporal_load(
                (const intx4*)(bpA1 + sup * 128 + half * 64 + st * 16));
        }
        return r;
    };

    // prologue: sup0 staged into buf0, first braw half in regs
    Half brP = load_half(sup0, 0);
    stage_issue(sup0);
    stage_commit(0);

    #pragma unroll 1
    for (int s = 0; s < nsup; ++s) {
        const int b = s & 1;
        const int sup = sup0 + s;
        __syncthreads();                       // drains prev DMA+loads; frees buf 1-b

        if (s + 1 < nsup) stage_issue(sup + 1);            // oldest in queue
        Half brQ = load_half(sup, 1);                      // used this iter (late)
        Half brPn;
        if (s + 1 < nsup) brPn = load_half(sup + 1, 0);    // used next iter

        // per-sup constants from LDS buf b
        const intx4  sv0 = scs[b][w * 32 + lo];
        const intx4  sv1 = scs[b][w * 32 + 16 + lo];
        const float2 dp0 = dds[b][w * 32 + lo];
        const float2 dp1 = dds[b][w * 32 + 16 + lo];
        const float a945_0 = dp0.x * (1.0f / 945.0f), a63_0 = dp0.x * (1.0f / 63.0f);
        const float a945_1 = dp1.x * (1.0f / 945.0f), a63_1 = dp1.x * (1.0f / 63.0f);

        auto compute_half = [&](int half, const Half& br) {
            #pragma unroll
            for (int st = 0; st < 4; ++st) {
                const int step = half * 4 + st;
                intx4 x0 = xfs[b][0 * 512 + step * 64 + l];
                intx4 x1 = xfs[b][1 * 512 + step * 64 + l];
                intx4 x2 = xfs[b][2 * 512 + step * 64 + l];
                intx4 x3 = xfs[b][3 * 512 + step * 64 + l];
                #pragma unroll
                for (int nt = 0; nt < 2; ++nt) {
                    const intx4 sv = nt ? sv1 : sv0;
                    const int scw = half ? sv.y : sv.x;
                    const int mnw = half ? sv.w : sv.z;
                    const float A = (nt ? a945_1 : a945_0) * (float)((scw >> (st * 8)) & 255);
                    const float B = fmaf((nt ? a63_1 : a63_0),
                                         (float)((mnw >> (st * 8)) & 255),
                                         (nt ? dp1.y : dp0.y));
                    const intx4 bv = br.v[nt][st];
                    union { intx4 i; short8 s8; } uw;
                    uw.i.x = pack_bf16(fmaf((float)(bv.x & 15), A, B),
                                       fmaf((float)(bv.x >> 4), A, B));
                    uw.i.y = pack_bf16(fmaf((float)(bv.y & 15), A, B),
                                       fmaf((float)(bv.y >> 4), A, B));
                    uw.i.z = pack_bf16(fmaf((float)(bv.z & 15), A, B),
                                       fmaf((float)(bv.z >> 4), A, B));
                    uw.i.w = pack_bf16(fmaf((float)(bv.w & 15), A, B),
                                       fmaf((float)(bv.w >> 4), A, B));
                    union { intx4 i; short8 s8; } u0, u1, u2, u3;
                    u0.i = x0; u1.i = x1; u2.i = x2; u3.i = x3;
                    acc[0][nt] = __builtin_amdgcn_mfma_f32_16x16x32_bf16(u0.s8, uw.s8, acc[0][nt], 0, 0, 0);
                    acc[1][nt] = __builtin_amdgcn_mfma_f32_16x16x32_bf16(u1.s8, uw.s8, acc[1][nt], 0, 0, 0);
                    acc[2][nt] = __builtin_amdgcn_mfma_f32_16x16x32_bf16(u2.s8, uw.s8, acc[2][nt], 0, 0, 0);
                    acc[3][nt] = __builtin_amdgcn_mfma_f32_16x16x32_bf16(u3.s8, uw.s8, acc[3][nt], 0, 0, 0);
                }
            }
        };

        compute_half(0, brP);
        compute_half(1, brQ);

        if (s + 1 < nsup) { stage_commit(1 - b); brP = brPn; }
    }

    // epilogue: D col = lane&15 -> o0/o1, row = mt*16 + hi*4 + r
    if (USE_PART) {
        float* p0 = part + (size_t)ks * (BATCH * OUT_F);
        #pragma unroll
        for (int mt = 0; mt < 4; ++mt) {
            #pragma unroll
            for (int r = 0; r < 4; ++r) {
                const int row = (mt * 16 + hi * 4 + r) * OUT_F;
                p0[row + o0] = acc[mt][0][r];
                p0[row + o1] = acc[mt][1][r];
            }
        }
    } else {
        #pragma unroll
        for (int mt = 0; mt < 4; ++mt) {
            #pragma unroll
            for (int r = 0; r < 4; ++r) {
                const int row = (mt * 16 + hi * 4 + r) * OUT_F;
                atomicAdd(out + row + o0, acc[mt][0][r]);
                atomicAdd(out + row + o1, acc[mt][1][r]);
            }
        }
    }
}

extern "C" void kernel_launch(void* const* d_in, const int* in_sizes, int n_in,
                              void* d_out, int out_size, void* d_ws, size_t ws_size,
                              hipStream_t stream) {
    (void)in_sizes; (void)n_in; (void)out_size;
    const float* x      = (const float*)d_in[0];
    const int*   packed = (const int*)d_in[1];
    const float* d      = (const float*)d_in[2];
    const float* dmin   = (const float*)d_in[3];
    const int*   scales = (const int*)d_in[4];
    const int*   mins   = (const int*)d_in[5];
    const float* bias   = (const float*)d_in[6];
    float* out = (float*)d_out;

    intx4*  xp     = (intx4*)d_ws;
    intx4*  scmn_p = (intx4*)((char*)d_ws + XP_BYTES);
    float2* ddm_p  = (float2*)((char*)d_ws + XP_BYTES + SCMN_BYTES);
    float*  part   = (float*)((char*)d_ws + PART_OFF);
    const bool has_part = ws_size >= (size_t)WS_FULL;

    xprep_kernel<<<344, 256, 0, stream>>>(x, xp);
    scprep_kernel<<<688, 256, 0, stream>>>(scales, mins, d, dmin, scmn_p, ddm_p);

    if (has_part) {
        qlin_main<true><<<NCB * NKS, 256, 0, stream>>>(
            xp, packed, scmn_p, ddm_p, part, out);
        reduce_kernel<<<(BATCH * OUT_F) / 256, 256, 0, stream>>>(part, bias, out);
    } else {
        init_out_kernel<<<(BATCH * OUT_F) / 256, 256, 0, stream>>>(bias, out);
        qlin_main<false><<<NCB * NKS, 256, 0, stream>>>(
            xp, packed, scmn_p, ddm_p, part, out);
    }
}